// Round 11
// baseline (2015.887 us; speedup 1.0000x reference)
//
#include <hip/hip_runtime.h>

typedef short s16x8 __attribute__((ext_vector_type(8)));
typedef float f32x4 __attribute__((ext_vector_type(4)));

// device-global scratch (outside d_ws; fully rewritten every launch)
__device__ short g_wbuf[18874368];  // bf16 weights, all layers: inproj|outw|ffw1|ffw2
__device__ short g_srcb[1048576];   // src as bf16 (16384 x 64)
__device__ short g_inpwb[32768];    // inp_w as bf16 (512 x 64)
__device__ short g_vt[8388608];     // V^T per layer: [b*8+h][d64][s512]
__device__ float g_pe[262144];      // positional encoding (512 x 512)
__device__ float g_hpart[256];      // head partials

__device__ inline float b2f(short s) {
  union { unsigned int u; float f; } v;
  v.u = ((unsigned int)(unsigned short)s) << 16;
  return v.f;
}
__device__ inline short f2b(float f) {
  union { float f; unsigned int u; } v; v.f = f;
  unsigned int r = (v.u + 0x7fffu + ((v.u >> 16) & 1u)) >> 16;
  return (short)r;
}
__device__ inline s16x8 pack8(float4 a, float4 b) {
  s16x8 r;
  r[0] = f2b(a.x); r[1] = f2b(a.y); r[2] = f2b(a.z); r[3] = f2b(a.w);
  r[4] = f2b(b.x); r[5] = f2b(b.y); r[6] = f2b(b.z); r[7] = f2b(b.w);
  return r;
}

__device__ inline f32x4 mfma16(s16x8 a, s16x8 b, f32x4 c) {
  return __builtin_amdgcn_mfma_f32_16x16x32_bf16(a, b, c, 0, 0, 0);
}

typedef const __attribute__((address_space(1))) void* as1cptr;
typedef __attribute__((address_space(3))) void* as3ptr;
__device__ inline void gl2lds16(const short* g, short* l) {
  __builtin_amdgcn_global_load_lds((as1cptr)g, (as3ptr)l, 16, 0, 0);
}

// ---------------- fp32 -> bf16 conversion kernels --------------------------
__global__ void __launch_bounds__(256)
cvt2_kernel(const float* __restrict__ i0, const float* __restrict__ i1) {
  const int b = blockIdx.x;
  const float* src; short* dst; int base;
  if (b < 512) { src = i0; dst = g_srcb; base = b; }
  else         { src = i1; dst = g_inpwb; base = b - 512; }
  const int idx = (base * 256 + threadIdx.x) * 8;
  float4 a = *(const float4*)(src + idx);
  float4 c = *(const float4*)(src + idx + 4);
  *(s16x8*)(dst + idx) = pack8(a, c);
}

// all 6 layers' weights: inproj(2304) | outw(768) | ffw1(3072) | ffw2(3072)
__global__ void __launch_bounds__(256)
cvt6_kernel(const float* __restrict__ i0, const float* __restrict__ i1,
            const float* __restrict__ i2, const float* __restrict__ i3) {
  const int b = blockIdx.x;
  const float* src; short* dst; int base;
  if (b < 2304)      { src = i0; dst = g_wbuf;            base = b; }
  else if (b < 3072) { src = i1; dst = g_wbuf +  4718592; base = b - 2304; }
  else if (b < 6144) { src = i2; dst = g_wbuf +  6291456; base = b - 3072; }
  else               { src = i3; dst = g_wbuf + 12582912; base = b - 6144; }
  const int idx = (base * 256 + threadIdx.x) * 8;
  float4 a = *(const float4*)(src + idx);
  float4 c = *(const float4*)(src + idx + 4);
  *(s16x8*)(dst + idx) = pack8(a, c);
}

// ---------------- PE table: g_pe[s][n] ------------------------------------
__global__ void __launch_bounds__(256)
pe_kernel() {
  const int s = blockIdx.x;
  const int n0 = threadIdx.x * 2;
  const float ang = (float)s * expf((float)n0 * -0.0179889460390160f);
  g_pe[s * 512 + n0]     = sinf(ang);
  g_pe[s * 512 + n0 + 1] = cosf(ang);
}

// ---------------- GEMM: C[M,N] = A[M,K] @ W[N,K]^T + epilogue -------------
// BK=64, XOR-swizzled gl2lds staging, 1D bn-major grid (unchanged from R10).
template <int EPI>
__global__ void __launch_bounds__(256, 3)
gemm_bt(const short* __restrict__ Ain, int woff, const float* __restrict__ bias,
        short* __restrict__ C, int M, int N, int K) {
  __shared__ short As[128 * 64];   // 16 KB
  __shared__ short Bs[128 * 64];   // 16 KB
  const int tid  = threadIdx.x;
  const int lane = tid & 63;
  const int wave = tid >> 6;
  const int wr = (wave >> 1) << 6;
  const int wc = (wave & 1) << 6;
  const int ml = lane & 15;
  const int quad = lane >> 4;
  const int bm = blockIdx.x & 127;
  const int bn = blockIdx.x >> 7;

  const short* A = (EPI == 2) ? (const short*)g_srcb : Ain;
  const short* W = (EPI == 2) ? (const short*)g_inpwb : (const short*)(g_wbuf + woff);

  int srow[4], soff[4];
#pragma unroll
  for (int i = 0; i < 4; ++i) {
    const int u = i * 256 + tid;
    srow[i] = u >> 3;
    soff[i] = ((u & 7) ^ ((u >> 3) & 7)) << 3;
  }
  const int rsw = (ml & 7);
  f32x4 acc[4][4] = {};

  for (int k0 = 0; k0 < K; k0 += 64) {
#pragma unroll
    for (int i = 0; i < 4; ++i) {
      gl2lds16(A + (size_t)(bm * 128 + srow[i]) * K + k0 + soff[i],
               As + (i * 256 + tid) * 8);
      gl2lds16(W + (size_t)(bn * 128 + srow[i]) * K + k0 + soff[i],
               Bs + (i * 256 + tid) * 8);
    }
    __syncthreads();
#pragma unroll
    for (int kk = 0; kk < 2; ++kk) {
      const int rchunk = ((kk * 4 + quad) ^ rsw) * 8;
      s16x8 af[4], bfr[4];
#pragma unroll
      for (int i = 0; i < 4; ++i)
        af[i] = *(const s16x8*)(As + (wr + i * 16 + ml) * 64 + rchunk);
#pragma unroll
      for (int j = 0; j < 4; ++j)
        bfr[j] = *(const s16x8*)(Bs + (wc + j * 16 + ml) * 64 + rchunk);
#pragma unroll
      for (int i = 0; i < 4; ++i)
#pragma unroll
        for (int j = 0; j < 4; ++j)
          acc[i][j] = mfma16(af[i], bfr[j], acc[i][j]);
    }
    __syncthreads();
  }

#pragma unroll
  for (int j = 0; j < 4; ++j) {
    const int col = bn * 128 + wc + j * 16 + ml;
    const float bv = bias[col];
#pragma unroll
    for (int i = 0; i < 4; ++i) {
      const int row0 = bm * 128 + wr + i * 16 + quad * 4;
#pragma unroll
      for (int r = 0; r < 4; ++r) {
        float v = acc[i][j][r] + bv;
        if (EPI == 1) v = fmaxf(v, 0.0f);
        if (EPI == 2) {
          const int s = (row0 + r) & 511;
          v = (acc[i][j][r] + bv) * 22.62741699796952f + g_pe[s * 512 + col];
        }
        C[(size_t)(row0 + r) * N + col] = f2b(v);
      }
    }
  }
}

// ---------------- V transpose: qkv V-part -> g_vt[bh][d][s] ---------------
// block = (bh 0..255) x (kt 0..3): LDS tile 128 keys x 64 d, both sides
// vectorized 16B.
__global__ void __launch_bounds__(256)
vtr_kernel(const short* __restrict__ qkv) {
  __shared__ short T[128 * 72];
  const int tid = threadIdx.x;
  const int kt = blockIdx.x & 3;
  const int bh = blockIdx.x >> 2;
  const int b = bh >> 3, h = bh & 7;
  const short* base = qkv + (size_t)b * 512 * 1536 + 1024 + h * 64;
#pragma unroll
  for (int i = 0; i < 4; ++i) {
    const int u = i * 256 + tid;
    const int key = u >> 3;
    const int d8 = (u & 7) << 3;
    *(s16x8*)(T + key * 72 + d8) =
        *(const s16x8*)(base + (size_t)(kt * 128 + key) * 1536 + d8);
  }
  __syncthreads();
  short* dst = g_vt + (size_t)bh * 32768 + kt * 128;
#pragma unroll
  for (int i = 0; i < 4; ++i) {
    const int u = i * 256 + tid;
    const int d = u >> 4;
    const int kc = (u & 15) * 8;
    s16x8 o;
#pragma unroll
    for (int j = 0; j < 8; ++j) o[j] = T[(kc + j) * 72 + d];
    *(s16x8*)(dst + d * 512 + kc) = o;
  }
}

// ---- block swizzle: same-(b,h) q-tiles land on one XCD within a 128-block
// window -> K/V/vt fetched once per XCD. bx = (bh&7) | (qt<<3) | ((bh>>3)<<7)
__device__ inline void attn_decode(int bx, int& qt, int& b, int& h) {
  qt = (bx >> 3) & 15;
  const int bh = (bx & 7) | ((bx >> 7) << 3);
  b = bh >> 3; h = bh & 7;
}

// ---------------- attention: barrier-free main loop -----------------------
// No K/V LDS staging: kf straight from qkv (L2-hot, XCD-affine), vf straight
// from g_vt. Wave (mt,nh) owns keys nh*32..+31 of each 64-key round; P is
// wave-private LDS (16x32, stride 36) -> zero barriers in the loop.
// MAXSUB=1 (layer 0): extra barrier-free QK pass for the exact row max
// (recompute is bit-identical -> exp arg <= 0 exactly).
template <int MAXSUB>
__global__ void __launch_bounds__(256, 4)
attn_nb_kernel(const short* __restrict__ qkv, short* __restrict__ ctx) {
  __shared__ float SM[4160];         // Pt overlay (4608B) then ob[2][32][65]
  __shared__ float rsum[2][2][16];
  const int tid = threadIdx.x;
  const int lane = tid & 63, wave = tid >> 6;
  const int ml = lane & 15, quad = lane >> 4;
  const int mt = wave & 1, nh = wave >> 1;
  int qt, b, h;
  attn_decode(blockIdx.x, qt, b, h);
  const size_t basebs = (size_t)b * 512 * 1536;
  const int hoff = h * 64;
  const short* kbase = qkv + basebs + 512 + hoff;          // [key][d]
  const short* vtb = g_vt + (size_t)(b * 8 + h) * 32768;   // [d][s]

  s16x8 qf0, qf1;
  {
    const int qrow = qt * 32 + mt * 16 + ml;
    const short* qp = qkv + basebs + (size_t)qrow * 1536 + hoff;
    qf0 = *(const s16x8*)(qp + quad * 8);
    qf1 = *(const s16x8*)(qp + 32 + quad * 8);
  }

  float rm[4] = {0.f, 0.f, 0.f, 0.f};
  if (MAXSUB) {
    f32x4 rmx = {-3e38f, -3e38f, -3e38f, -3e38f};
#pragma unroll
    for (int rr = 0; rr < 8; ++rr) {
#pragma unroll
      for (int nt = 0; nt < 2; ++nt) {
        const int nrow = rr * 64 + nh * 32 + nt * 16 + ml;
        const short* kp = kbase + (size_t)nrow * 1536;
        f32x4 sacc = {};
        sacc = mfma16(qf0, *(const s16x8*)(kp + quad * 8), sacc);
        sacc = mfma16(qf1, *(const s16x8*)(kp + 32 + quad * 8), sacc);
#pragma unroll
        for (int r = 0; r < 4; ++r) rmx[r] = fmaxf(rmx[r], sacc[r]);
      }
    }
#pragma unroll
    for (int off = 1; off <= 8; off <<= 1)
#pragma unroll
      for (int r = 0; r < 4; ++r)
        rmx[r] = fmaxf(rmx[r], __shfl_xor(rmx[r], off));
    if (ml == 0) {
#pragma unroll
      for (int r = 0; r < 4; ++r) rsum[nh][mt][quad * 4 + r] = rmx[r];
    }
    __syncthreads();
#pragma unroll
    for (int r = 0; r < 4; ++r)
      rm[r] = 0.125f * fmaxf(rsum[0][mt][quad * 4 + r], rsum[1][mt][quad * 4 + r]);
    __syncthreads();   // rsum reused for psum later
  }

  short* Ptw = (short*)SM + wave * 576;   // 16 rows x stride 36
  f32x4 oacc[4] = {};
  float psum[4] = {0.f, 0.f, 0.f, 0.f};

  for (int rr = 0; rr < 8; ++rr) {
    // vf loads issued early; consumed at the end of the round
    s16x8 vf[4];
#pragma unroll
    for (int nt2 = 0; nt2 < 4; ++nt2)
      vf[nt2] = *(const s16x8*)(vtb + (nt2 * 16 + ml) * 512 + rr * 64 + nh * 32 + quad * 8);
#pragma unroll
    for (int nt = 0; nt < 2; ++nt) {
      const int nrow = rr * 64 + nh * 32 + nt * 16 + ml;
      const short* kp = kbase + (size_t)nrow * 1536;
      f32x4 sacc = {};
      sacc = mfma16(qf0, *(const s16x8*)(kp + quad * 8), sacc);
      sacc = mfma16(qf1, *(const s16x8*)(kp + 32 + quad * 8), sacc);
#pragma unroll
      for (int r = 0; r < 4; ++r) {
        const float p = __expf(sacc[r] * 0.125f - rm[r]);
        const short pb = f2b(p);
        psum[r] += b2f(pb);
        Ptw[(quad * 4 + r) * 36 + nt * 16 + ml] = pb;   // wave-private
      }
    }
    const s16x8 pf = *(const s16x8*)(Ptw + ml * 36 + quad * 8);
#pragma unroll
    for (int nt2 = 0; nt2 < 4; ++nt2)
      oacc[nt2] = mfma16(pf, vf[nt2], oacc[nt2]);
  }

  // row sums: shuffle over ml, publish per (nh,mt)
#pragma unroll
  for (int off = 1; off <= 8; off <<= 1)
#pragma unroll
    for (int r = 0; r < 4; ++r)
      psum[r] += __shfl_xor(psum[r], off);
  if (ml == 0) {
#pragma unroll
    for (int r = 0; r < 4; ++r) rsum[nh][mt][quad * 4 + r] = psum[r];
  }
  __syncthreads();   // all Pt use done; SM becomes ob

  float* ob = SM;    // [nh][row32][d64] stride 65
#pragma unroll
  for (int nt2 = 0; nt2 < 4; ++nt2)
#pragma unroll
    for (int r = 0; r < 4; ++r)
      ob[nh * 2080 + (mt * 16 + quad * 4 + r) * 65 + nt2 * 16 + ml] = oacc[nt2][r];
  __syncthreads();

  {
    const int row = tid >> 3;
    const int dg = (tid & 7) * 8;
    const float l = rsum[0][row >> 4][row & 15] + rsum[1][row >> 4][row & 15];
    const float rl = 1.0f / l;
    s16x8 outv;
#pragma unroll
    for (int i = 0; i < 8; ++i) {
      const float o = ob[row * 65 + dg + i] + ob[2080 + row * 65 + dg + i];
      outv[i] = f2b(o * rl);
    }
    *(s16x8*)(ctx + ((size_t)b * 512 + qt * 32 + row) * 512 + hoff + dg) = outv;
  }
}

// ---------------- residual + layernorm (in-place on x, fp32 params) -------
__global__ void __launch_bounds__(256)
ln_kernel(short* __restrict__ x, const short* __restrict__ o,
          const float* __restrict__ g, const float* __restrict__ bta) {
  const int row = blockIdx.x * 4 + (threadIdx.x >> 6);
  const int lane = threadIdx.x & 63;
  short* xp = x + (size_t)row * 512 + lane * 8;
  const short* op = o + (size_t)row * 512 + lane * 8;
  s16x8 xv = *(const s16x8*)xp;
  s16x8 ov = *(const s16x8*)op;
  float v[8]; float s = 0.f, s2 = 0.f;
#pragma unroll
  for (int e = 0; e < 8; ++e) {
    float f = b2f(xv[e]) + b2f(ov[e]);
    v[e] = f; s += f; s2 += f * f;
  }
#pragma unroll
  for (int off = 32; off >= 1; off >>= 1) {
    s += __shfl_xor(s, off);
    s2 += __shfl_xor(s2, off);
  }
  const float mean = s * (1.f / 512.f);
  const float var = s2 * (1.f / 512.f) - mean * mean;
  const float rstd = rsqrtf(var + 1e-5f);
  float4 g0 = *(const float4*)(g + lane * 8);
  float4 g1 = *(const float4*)(g + lane * 8 + 4);
  float4 b0 = *(const float4*)(bta + lane * 8);
  float4 b1 = *(const float4*)(bta + lane * 8 + 4);
  float gv[8] = {g0.x, g0.y, g0.z, g0.w, g1.x, g1.y, g1.z, g1.w};
  float bv[8] = {b0.x, b0.y, b0.z, b0.w, b1.x, b1.y, b1.z, b1.w};
  s16x8 outv;
#pragma unroll
  for (int e = 0; e < 8; ++e)
    outv[e] = f2b((v[e] - mean) * rstd * gv[e] + bv[e]);
  *(s16x8*)xp = outv;
}

// ---------------- head ----------------------------------------------------
__global__ void __launch_bounds__(256)
head1_kernel(const short* __restrict__ x, const float* __restrict__ w1,
             const float* __restrict__ b1, const float* __restrict__ w2) {
  const int bidx = blockIdx.x;
  const int b = bidx >> 3, seg = bidx & 7;
  const int tid = threadIdx.x;
  __shared__ float xl[512];
  __shared__ float red[256];
  for (int n = tid; n < 512; n += 256)
    xl[n] = b2f(x[((size_t)b * 512 + 511) * 512 + n]);
  __syncthreads();
  const int f = seg * 256 + tid;
  const float* wr = w1 + (size_t)f * 512;
  float hv = 0.f;
  for (int k8 = 0; k8 < 64; ++k8) {
    float4 wa = *(const float4*)(wr + k8 * 8);
    float4 wb = *(const float4*)(wr + k8 * 8 + 4);
    hv += xl[k8 * 8 + 0] * wa.x + xl[k8 * 8 + 1] * wa.y +
          xl[k8 * 8 + 2] * wa.z + xl[k8 * 8 + 3] * wa.w +
          xl[k8 * 8 + 4] * wb.x + xl[k8 * 8 + 5] * wb.y +
          xl[k8 * 8 + 6] * wb.z + xl[k8 * 8 + 7] * wb.w;
  }
  hv += b1[f];
  hv = fmaxf(hv, 0.f);
  red[tid] = hv * w2[f];
  __syncthreads();
  for (int stride = 128; stride > 0; stride >>= 1) {
    if (tid < stride) red[tid] += red[tid + stride];
    __syncthreads();
  }
  if (tid == 0) g_hpart[bidx] = red[0];
}

__global__ void __launch_bounds__(64)
head2_kernel(const float* __restrict__ b2, float* __restrict__ out) {
  const int t = threadIdx.x;
  if (t < 32) {
    float s = 0.f;
#pragma unroll
    for (int c = 0; c < 8; ++c) s += g_hpart[t * 8 + c];
    out[t] = s + b2[0];
  }
}

extern "C" void kernel_launch(void* const* d_in, const int* in_sizes, int n_in,
                              void* d_out, int out_size, void* d_ws, size_t ws_size,
                              hipStream_t stream) {
  (void)in_sizes; (void)n_in; (void)out_size; (void)ws_size;
  const float* src       = (const float*)d_in[0];
  const float* inp_w     = (const float*)d_in[1];
  const float* inp_b     = (const float*)d_in[2];
  const float* in_proj_w = (const float*)d_in[3];
  const float* in_proj_b = (const float*)d_in[4];
  const float* out_w     = (const float*)d_in[5];
  const float* out_b     = (const float*)d_in[6];
  const float* ff_w1     = (const float*)d_in[7];
  const float* ff_b1     = (const float*)d_in[8];
  const float* ff_w2     = (const float*)d_in[9];
  const float* ff_b2     = (const float*)d_in[10];
  const float* ln1_g     = (const float*)d_in[11];
  const float* ln1_b     = (const float*)d_in[12];
  const float* ln2_g     = (const float*)d_in[13];
  const float* ln2_b     = (const float*)d_in[14];
  const float* op_w1     = (const float*)d_in[15];
  const float* op_b1     = (const float*)d_in[16];
  const float* op_w2     = (const float*)d_in[17];
  const float* op_b2     = (const float*)d_in[18];

  short* ws   = (short*)d_ws;
  short* x    = ws;                              //  8,388,608
  short* qkv  = ws + 8388608;                    // 25,165,824
  short* ctx  = qkv + 25165824;                  //  8,388,608
  short* obuf = ctx + 8388608;                   //  8,388,608
  short* h    = qkv;                             // ff hidden spans qkv+ctx

  cvt2_kernel<<<528, 256, 0, stream>>>(src, inp_w);
  cvt6_kernel<<<9216, 256, 0, stream>>>(in_proj_w, out_w, ff_w1, ff_w2);
  pe_kernel<<<512, 256, 0, stream>>>();
  gemm_bt<2><<<512, 256, 0, stream>>>(nullptr, 0, inp_b, x, 16384, 512, 64);

  for (int l = 0; l < 6; ++l) {
    const int w_qkv = l * 786432;
    const int w_out = 4718592 + l * 262144;
    const int w_ff1 = 6291456 + l * 1048576;
    const int w_ff2 = 12582912 + l * 1048576;
    gemm_bt<0><<<1536, 256, 0, stream>>>(
        x, w_qkv, in_proj_b + l * 1536, qkv, 16384, 1536, 512);
    vtr_kernel<<<1024, 256, 0, stream>>>(qkv);
    if (l == 0)
      attn_nb_kernel<1><<<4096, 256, 0, stream>>>(qkv, ctx);
    else
      attn_nb_kernel<0><<<4096, 256, 0, stream>>>(qkv, ctx);
    gemm_bt<0><<<512, 256, 0, stream>>>(
        ctx, w_out, out_b + l * 512, obuf, 16384, 512, 512);
    ln_kernel<<<4096, 256, 0, stream>>>(x, obuf, ln1_g + l * 512, ln1_b + l * 512);
    gemm_bt<1><<<2048, 256, 0, stream>>>(
        x, w_ff1, ff_b1 + l * 2048, h, 16384, 2048, 512);
    gemm_bt<0><<<512, 256, 0, stream>>>(
        h, w_ff2, ff_b2 + l * 512, obuf, 16384, 512, 2048);
    ln_kernel<<<4096, 256, 0, stream>>>(x, obuf, ln2_g + l * 512, ln2_b + l * 512);
  }
  head1_kernel<<<256, 256, 0, stream>>>(x, op_w1, op_b1, op_w2);
  head2_kernel<<<1, 64, 0, stream>>>(op_b2, (float*)d_out);
}

// Round 12
// 1583.723 us; speedup vs baseline: 1.2729x; 1.2729x over previous
//
#include <hip/hip_runtime.h>

typedef short s16x8 __attribute__((ext_vector_type(8)));
typedef float f32x4 __attribute__((ext_vector_type(4)));

// device-global scratch (outside d_ws; fully rewritten every launch)
__device__ short g_wbuf[18874368];  // bf16 weights, all layers: inproj|outw|ffw1|ffw2
__device__ short g_srcb[1048576];   // src as bf16 (16384 x 64)
__device__ short g_inpwb[32768];    // inp_w as bf16 (512 x 64)
__device__ float g_pe[262144];      // positional encoding (512 x 512)
__device__ float g_hpart[256];      // head partials

__device__ inline float b2f(short s) {
  union { unsigned int u; float f; } v;
  v.u = ((unsigned int)(unsigned short)s) << 16;
  return v.f;
}
__device__ inline short f2b(float f) {
  union { float f; unsigned int u; } v; v.f = f;
  unsigned int r = (v.u + 0x7fffu + ((v.u >> 16) & 1u)) >> 16;
  return (short)r;
}
__device__ inline s16x8 pack8(float4 a, float4 b) {
  s16x8 r;
  r[0] = f2b(a.x); r[1] = f2b(a.y); r[2] = f2b(a.z); r[3] = f2b(a.w);
  r[4] = f2b(b.x); r[5] = f2b(b.y); r[6] = f2b(b.z); r[7] = f2b(b.w);
  return r;
}

__device__ inline f32x4 mfma16(s16x8 a, s16x8 b, f32x4 c) {
  return __builtin_amdgcn_mfma_f32_16x16x32_bf16(a, b, c, 0, 0, 0);
}

typedef const __attribute__((address_space(1))) void* as1cptr;
typedef __attribute__((address_space(3))) void* as3ptr;
__device__ inline void gl2lds16(const short* g, short* l) {
  __builtin_amdgcn_global_load_lds((as1cptr)g, (as3ptr)l, 16, 0, 0);
}

// ---------------- fp32 -> bf16 conversion kernels --------------------------
__global__ void __launch_bounds__(256)
cvt2_kernel(const float* __restrict__ i0, const float* __restrict__ i1) {
  const int b = blockIdx.x;
  const float* src; short* dst; int base;
  if (b < 512) { src = i0; dst = g_srcb; base = b; }
  else         { src = i1; dst = g_inpwb; base = b - 512; }
  const int idx = (base * 256 + threadIdx.x) * 8;
  float4 a = *(const float4*)(src + idx);
  float4 c = *(const float4*)(src + idx + 4);
  *(s16x8*)(dst + idx) = pack8(a, c);
}

// all 6 layers' weights: inproj(2304) | outw(768) | ffw1(3072) | ffw2(3072)
__global__ void __launch_bounds__(256)
cvt6_kernel(const float* __restrict__ i0, const float* __restrict__ i1,
            const float* __restrict__ i2, const float* __restrict__ i3) {
  const int b = blockIdx.x;
  const float* src; short* dst; int base;
  if (b < 2304)      { src = i0; dst = g_wbuf;            base = b; }
  else if (b < 3072) { src = i1; dst = g_wbuf +  4718592; base = b - 2304; }
  else if (b < 6144) { src = i2; dst = g_wbuf +  6291456; base = b - 3072; }
  else               { src = i3; dst = g_wbuf + 12582912; base = b - 6144; }
  const int idx = (base * 256 + threadIdx.x) * 8;
  float4 a = *(const float4*)(src + idx);
  float4 c = *(const float4*)(src + idx + 4);
  *(s16x8*)(dst + idx) = pack8(a, c);
}

// ---------------- PE table: g_pe[s][n] ------------------------------------
__global__ void __launch_bounds__(256)
pe_kernel() {
  const int s = blockIdx.x;
  const int n0 = threadIdx.x * 2;
  const float ang = (float)s * expf((float)n0 * -0.0179889460390160f);
  g_pe[s * 512 + n0]     = sinf(ang);
  g_pe[s * 512 + n0 + 1] = cosf(ang);
}

// ---------------- GEMM: C[M,N] = A[M,K] @ W[N,K]^T + epilogue -------------
// BK=64, XOR-swizzled gl2lds staging, 1D bn-major grid.
template <int EPI>
__global__ void __launch_bounds__(256, 3)
gemm_bt(const short* __restrict__ Ain, int woff, const float* __restrict__ bias,
        short* __restrict__ C, int M, int N, int K) {
  __shared__ short As[128 * 64];   // 16 KB
  __shared__ short Bs[128 * 64];   // 16 KB
  const int tid  = threadIdx.x;
  const int lane = tid & 63;
  const int wave = tid >> 6;
  const int wr = (wave >> 1) << 6;
  const int wc = (wave & 1) << 6;
  const int ml = lane & 15;
  const int quad = lane >> 4;
  const int bm = blockIdx.x & 127;
  const int bn = blockIdx.x >> 7;

  const short* A = (EPI == 2) ? (const short*)g_srcb : Ain;
  const short* W = (EPI == 2) ? (const short*)g_inpwb : (const short*)(g_wbuf + woff);

  int srow[4], soff[4];
#pragma unroll
  for (int i = 0; i < 4; ++i) {
    const int u = i * 256 + tid;
    srow[i] = u >> 3;
    soff[i] = ((u & 7) ^ ((u >> 3) & 7)) << 3;
  }
  const int rsw = (ml & 7);
  f32x4 acc[4][4] = {};

  for (int k0 = 0; k0 < K; k0 += 64) {
#pragma unroll
    for (int i = 0; i < 4; ++i) {
      gl2lds16(A + (size_t)(bm * 128 + srow[i]) * K + k0 + soff[i],
               As + (i * 256 + tid) * 8);
      gl2lds16(W + (size_t)(bn * 128 + srow[i]) * K + k0 + soff[i],
               Bs + (i * 256 + tid) * 8);
    }
    __syncthreads();
#pragma unroll
    for (int kk = 0; kk < 2; ++kk) {
      const int rchunk = ((kk * 4 + quad) ^ rsw) * 8;
      s16x8 af[4], bfr[4];
#pragma unroll
      for (int i = 0; i < 4; ++i)
        af[i] = *(const s16x8*)(As + (wr + i * 16 + ml) * 64 + rchunk);
#pragma unroll
      for (int j = 0; j < 4; ++j)
        bfr[j] = *(const s16x8*)(Bs + (wc + j * 16 + ml) * 64 + rchunk);
#pragma unroll
      for (int i = 0; i < 4; ++i)
#pragma unroll
        for (int j = 0; j < 4; ++j)
          acc[i][j] = mfma16(af[i], bfr[j], acc[i][j]);
    }
    __syncthreads();
  }

#pragma unroll
  for (int j = 0; j < 4; ++j) {
    const int col = bn * 128 + wc + j * 16 + ml;
    const float bv = bias[col];
#pragma unroll
    for (int i = 0; i < 4; ++i) {
      const int row0 = bm * 128 + wr + i * 16 + quad * 4;
#pragma unroll
      for (int r = 0; r < 4; ++r) {
        float v = acc[i][j][r] + bv;
        if (EPI == 1) v = fmaxf(v, 0.0f);
        if (EPI == 2) {
          const int s = (row0 + r) & 511;
          v = (acc[i][j][r] + bv) * 22.62741699796952f + g_pe[s * 512 + col];
        }
        C[(size_t)(row0 + r) * N + col] = f2b(v);
      }
    }
  }
}

// ---- block swizzle: same-(b,h) q-tiles land on one XCD within a 128-block
// window -> K/V fetched once per XCD. bx = (bh&7) | (qt<<3) | ((bh>>3)<<7)
__device__ inline void attn_decode(int bx, int& qt, int& b, int& h) {
  qt = (bx >> 3) & 15;
  const int bh = (bx & 7) | ((bx >> 7) << 3);
  b = bh >> 3; h = bh & 7;
}

// ---------------- attention: R9 two-phase kernel (best measured: 85 us)
// + XCD swizzle. Coalesced LDS staging of K and V (the R11 lesson: staging
// IS the latency->throughput converter), scores in regs sc[8][2], exact max.
__global__ void __launch_bounds__(256, 4)
attn_kernel(const short* __restrict__ qkv, short* __restrict__ ctx) {
  __shared__ short KT[64 * 72];      // [key][d]
  __shared__ short VT[64 * 72];      // [d][key]
  __shared__ short Pt[32 * 72];      // [row][key]
  __shared__ float rcomb[2][2][16];
  const int tid = threadIdx.x;
  const int lane = tid & 63, wave = tid >> 6;
  const int ml = lane & 15, quad = lane >> 4;
  const int mt = wave & 1, nh = wave >> 1;
  int qt, b, h;
  attn_decode(blockIdx.x, qt, b, h);
  const size_t basebs = (size_t)b * 512 * 1536;
  const int hoff = h * 64;

  s16x8 qf0, qf1;
  {
    const int qrow = qt * 32 + mt * 16 + ml;
    const short* qp = qkv + basebs + (size_t)qrow * 1536 + hoff;
    qf0 = *(const s16x8*)(qp + quad * 8);
    qf1 = *(const s16x8*)(qp + 32 + quad * 8);
  }

  // ---- phase 1: all scores into registers (8 rounds x 64 keys) ----
  f32x4 sc[8][2];
#pragma unroll
  for (int rr = 0; rr < 8; ++rr) {
#pragma unroll
    for (int i = 0; i < 2; ++i) {          // stage 64 keys x 64 d (coalesced)
      int u = i * 256 + tid;
      int key = u >> 3;
      int d8 = (u & 7) << 3;
      const short* kp = qkv + basebs + (size_t)(rr * 64 + key) * 1536 + 512 + hoff + d8;
      *(s16x8*)(KT + key * 72 + d8) = *(const s16x8*)kp;
    }
    __syncthreads();
#pragma unroll
    for (int nt = 0; nt < 2; ++nt) {
      const int nrow = nh * 32 + nt * 16 + ml;
      f32x4 sacc = {};
      s16x8 kf0 = *(const s16x8*)(KT + nrow * 72 + quad * 8);
      s16x8 kf1 = *(const s16x8*)(KT + nrow * 72 + 32 + quad * 8);
      sacc = mfma16(qf0, kf0, sacc);
      sacc = mfma16(qf1, kf1, sacc);
      sc[rr][nt] = sacc;
    }
    __syncthreads();
  }

  // ---- exact row max ----
  f32x4 rmx = sc[0][0];
#pragma unroll
  for (int rr = 0; rr < 8; ++rr)
#pragma unroll
    for (int nt = 0; nt < 2; ++nt)
#pragma unroll
      for (int r = 0; r < 4; ++r)
        rmx[r] = fmaxf(rmx[r], sc[rr][nt][r]);
#pragma unroll
  for (int off = 1; off <= 8; off <<= 1)
#pragma unroll
    for (int r = 0; r < 4; ++r)
      rmx[r] = fmaxf(rmx[r], __shfl_xor(rmx[r], off));
  if (ml == 0) {
#pragma unroll
    for (int r = 0; r < 4; ++r)
      rcomb[nh][mt][quad * 4 + r] = rmx[r];
  }
  __syncthreads();
  float rm[4];
#pragma unroll
  for (int r = 0; r < 4; ++r)
    rm[r] = 0.125f * fmaxf(rcomb[0][mt][quad * 4 + r], rcomb[1][mt][quad * 4 + r]);

  // ---- phase 2: exp -> Pt, V^T stage, PV MFMA (8 rounds) ----
  f32x4 oacc[2] = {};
  float psum[4] = {0.f, 0.f, 0.f, 0.f};
#pragma unroll
  for (int rr = 0; rr < 8; ++rr) {
#pragma unroll
    for (int nt = 0; nt < 2; ++nt) {
#pragma unroll
      for (int r = 0; r < 4; ++r) {
        float p = __expf(sc[rr][nt][r] * 0.125f - rm[r]);   // arg <= 0 exactly
        short pb = f2b(p);
        psum[r] += b2f(pb);
        Pt[(mt * 16 + quad * 4 + r) * 72 + nh * 32 + nt * 16 + ml] = pb;
      }
    }
#pragma unroll
    for (int i = 0; i < 4; ++i) {          // stage V^T tile [d][key]
      int u = i * 256 + tid;
      int kp = u >> 5;
      int dp = u & 31;
      const short* vp = qkv + basebs + (size_t)(rr * 64 + kp * 2) * 1536 + 1024 + hoff + dp * 2;
      unsigned int u0 = *(const unsigned int*)vp;
      unsigned int u1 = *(const unsigned int*)(vp + 1536);
      *(unsigned int*)(VT + (dp * 2) * 72 + kp * 2) = (u0 & 0xffffu) | (u1 << 16);
      *(unsigned int*)(VT + (dp * 2 + 1) * 72 + kp * 2) = (u0 >> 16) | (u1 & 0xffff0000u);
    }
    __syncthreads();
#pragma unroll
    for (int ks = 0; ks < 2; ++ks) {
      s16x8 pf = *(const s16x8*)(Pt + (mt * 16 + ml) * 72 + ks * 32 + quad * 8);
#pragma unroll
      for (int n2 = 0; n2 < 2; ++n2) {
        const int nd = (nh * 2 + n2) * 16 + ml;
        s16x8 vf = *(const s16x8*)(VT + nd * 72 + ks * 32 + quad * 8);
        oacc[n2] = mfma16(pf, vf, oacc[n2]);
      }
    }
    __syncthreads();
  }

  // ---- row sums ----
#pragma unroll
  for (int off = 1; off <= 8; off <<= 1)
#pragma unroll
    for (int r = 0; r < 4; ++r)
      psum[r] += __shfl_xor(psum[r], off);
  if (ml == 0) {
#pragma unroll
    for (int r = 0; r < 4; ++r)
      rcomb[nh][mt][quad * 4 + r] = psum[r];
  }
  __syncthreads();

#pragma unroll
  for (int r = 0; r < 4; ++r) {
    const int srow = mt * 16 + quad * 4 + r;
    const float l = rcomb[0][mt][quad * 4 + r] + rcomb[1][mt][quad * 4 + r];
    const float rl = 1.0f / l;
    const int grow = qt * 32 + srow;
#pragma unroll
    for (int n2 = 0; n2 < 2; ++n2) {
      const int d = (nh * 2 + n2) * 16 + ml;
      ctx[((size_t)b * 512 + grow) * 512 + hoff + d] = f2b(oacc[n2][r] * rl);
    }
  }
}

// ---------------- residual + layernorm (in-place on x, fp32 params) -------
__global__ void __launch_bounds__(256)
ln_kernel(short* __restrict__ x, const short* __restrict__ o,
          const float* __restrict__ g, const float* __restrict__ bta) {
  const int row = blockIdx.x * 4 + (threadIdx.x >> 6);
  const int lane = threadIdx.x & 63;
  short* xp = x + (size_t)row * 512 + lane * 8;
  const short* op = o + (size_t)row * 512 + lane * 8;
  s16x8 xv = *(const s16x8*)xp;
  s16x8 ov = *(const s16x8*)op;
  float v[8]; float s = 0.f, s2 = 0.f;
#pragma unroll
  for (int e = 0; e < 8; ++e) {
    float f = b2f(xv[e]) + b2f(ov[e]);
    v[e] = f; s += f; s2 += f * f;
  }
#pragma unroll
  for (int off = 32; off >= 1; off >>= 1) {
    s += __shfl_xor(s, off);
    s2 += __shfl_xor(s2, off);
  }
  const float mean = s * (1.f / 512.f);
  const float var = s2 * (1.f / 512.f) - mean * mean;
  const float rstd = rsqrtf(var + 1e-5f);
  float4 g0 = *(const float4*)(g + lane * 8);
  float4 g1 = *(const float4*)(g + lane * 8 + 4);
  float4 b0 = *(const float4*)(bta + lane * 8);
  float4 b1 = *(const float4*)(bta + lane * 8 + 4);
  float gv[8] = {g0.x, g0.y, g0.z, g0.w, g1.x, g1.y, g1.z, g1.w};
  float bv[8] = {b0.x, b0.y, b0.z, b0.w, b1.x, b1.y, b1.z, b1.w};
  s16x8 outv;
#pragma unroll
  for (int e = 0; e < 8; ++e)
    outv[e] = f2b((v[e] - mean) * rstd * gv[e] + bv[e]);
  *(s16x8*)xp = outv;
}

// ---------------- head ----------------------------------------------------
__global__ void __launch_bounds__(256)
head1_kernel(const short* __restrict__ x, const float* __restrict__ w1,
             const float* __restrict__ b1, const float* __restrict__ w2) {
  const int bidx = blockIdx.x;
  const int b = bidx >> 3, seg = bidx & 7;
  const int tid = threadIdx.x;
  __shared__ float xl[512];
  __shared__ float red[256];
  for (int n = tid; n < 512; n += 256)
    xl[n] = b2f(x[((size_t)b * 512 + 511) * 512 + n]);
  __syncthreads();
  const int f = seg * 256 + tid;
  const float* wr = w1 + (size_t)f * 512;
  float hv = 0.f;
  for (int k8 = 0; k8 < 64; ++k8) {
    float4 wa = *(const float4*)(wr + k8 * 8);
    float4 wb = *(const float4*)(wr + k8 * 8 + 4);
    hv += xl[k8 * 8 + 0] * wa.x + xl[k8 * 8 + 1] * wa.y +
          xl[k8 * 8 + 2] * wa.z + xl[k8 * 8 + 3] * wa.w +
          xl[k8 * 8 + 4] * wb.x + xl[k8 * 8 + 5] * wb.y +
          xl[k8 * 8 + 6] * wb.z + xl[k8 * 8 + 7] * wb.w;
  }
  hv += b1[f];
  hv = fmaxf(hv, 0.f);
  red[tid] = hv * w2[f];
  __syncthreads();
  for (int stride = 128; stride > 0; stride >>= 1) {
    if (tid < stride) red[tid] += red[tid + stride];
    __syncthreads();
  }
  if (tid == 0) g_hpart[bidx] = red[0];
}

__global__ void __launch_bounds__(64)
head2_kernel(const float* __restrict__ b2, float* __restrict__ out) {
  const int t = threadIdx.x;
  if (t < 32) {
    float s = 0.f;
#pragma unroll
    for (int c = 0; c < 8; ++c) s += g_hpart[t * 8 + c];
    out[t] = s + b2[0];
  }
}

extern "C" void kernel_launch(void* const* d_in, const int* in_sizes, int n_in,
                              void* d_out, int out_size, void* d_ws, size_t ws_size,
                              hipStream_t stream) {
  (void)in_sizes; (void)n_in; (void)out_size; (void)ws_size;
  const float* src       = (const float*)d_in[0];
  const float* inp_w     = (const float*)d_in[1];
  const float* inp_b     = (const float*)d_in[2];
  const float* in_proj_w = (const float*)d_in[3];
  const float* in_proj_b = (const float*)d_in[4];
  const float* out_w     = (const float*)d_in[5];
  const float* out_b     = (const float*)d_in[6];
  const float* ff_w1     = (const float*)d_in[7];
  const float* ff_b1     = (const float*)d_in[8];
  const float* ff_w2     = (const float*)d_in[9];
  const float* ff_b2     = (const float*)d_in[10];
  const float* ln1_g     = (const float*)d_in[11];
  const float* ln1_b     = (const float*)d_in[12];
  const float* ln2_g     = (const float*)d_in[13];
  const float* ln2_b     = (const float*)d_in[14];
  const float* op_w1     = (const float*)d_in[15];
  const float* op_b1     = (const float*)d_in[16];
  const float* op_w2     = (const float*)d_in[17];
  const float* op_b2     = (const float*)d_in[18];

  short* ws   = (short*)d_ws;
  short* x    = ws;                              //  8,388,608
  short* qkv  = ws + 8388608;                    // 25,165,824
  short* ctx  = qkv + 25165824;                  //  8,388,608
  short* obuf = ctx + 8388608;                   //  8,388,608
  short* h    = qkv;                             // ff hidden spans qkv+ctx

  cvt2_kernel<<<528, 256, 0, stream>>>(src, inp_w);
  cvt6_kernel<<<9216, 256, 0, stream>>>(in_proj_w, out_w, ff_w1, ff_w2);
  pe_kernel<<<512, 256, 0, stream>>>();
  gemm_bt<2><<<512, 256, 0, stream>>>(nullptr, 0, inp_b, x, 16384, 512, 64);

  for (int l = 0; l < 6; ++l) {
    const int w_qkv = l * 786432;
    const int w_out = 4718592 + l * 262144;
    const int w_ff1 = 6291456 + l * 1048576;
    const int w_ff2 = 12582912 + l * 1048576;
    gemm_bt<0><<<1536, 256, 0, stream>>>(
        x, w_qkv, in_proj_b + l * 1536, qkv, 16384, 1536, 512);
    attn_kernel<<<4096, 256, 0, stream>>>(qkv, ctx);
    gemm_bt<0><<<512, 256, 0, stream>>>(
        ctx, w_out, out_b + l * 512, obuf, 16384, 512, 512);
    ln_kernel<<<4096, 256, 0, stream>>>(x, obuf, ln1_g + l * 512, ln1_b + l * 512);
    gemm_bt<1><<<2048, 256, 0, stream>>>(
        x, w_ff1, ff_b1 + l * 2048, h, 16384, 2048, 512);
    gemm_bt<0><<<512, 256, 0, stream>>>(
        h, w_ff2, ff_b2 + l * 512, obuf, 16384, 512, 2048);
    ln_kernel<<<4096, 256, 0, stream>>>(x, obuf, ln2_g + l * 512, ln2_b + l * 512);
  }
  head1_kernel<<<256, 256, 0, stream>>>(x, op_w1, op_b1, op_w2);
  head2_kernel<<<1, 64, 0, stream>>>(op_b2, (float*)d_out);
}

// Round 13
// 1550.244 us; speedup vs baseline: 1.3004x; 1.0216x over previous
//
#include <hip/hip_runtime.h>

typedef short s16x8 __attribute__((ext_vector_type(8)));
typedef float f32x4 __attribute__((ext_vector_type(4)));

// device-global scratch (outside d_ws; fully rewritten every launch)
__device__ short g_wbuf[18874368];  // bf16 weights, all layers: inproj|outw|ffw1|ffw2
__device__ short g_srcb[1048576];   // src as bf16 (16384 x 64)
__device__ short g_inpwb[32768];    // inp_w as bf16 (512 x 64)
__device__ float g_pe[262144];      // positional encoding (512 x 512)
__device__ float g_hpart[256];      // head partials

__device__ inline float b2f(short s) {
  union { unsigned int u; float f; } v;
  v.u = ((unsigned int)(unsigned short)s) << 16;
  return v.f;
}
__device__ inline short f2b(float f) {
  union { float f; unsigned int u; } v; v.f = f;
  unsigned int r = (v.u + 0x7fffu + ((v.u >> 16) & 1u)) >> 16;
  return (short)r;
}
__device__ inline s16x8 pack8(float4 a, float4 b) {
  s16x8 r;
  r[0] = f2b(a.x); r[1] = f2b(a.y); r[2] = f2b(a.z); r[3] = f2b(a.w);
  r[4] = f2b(b.x); r[5] = f2b(b.y); r[6] = f2b(b.z); r[7] = f2b(b.w);
  return r;
}

__device__ inline f32x4 mfma16(s16x8 a, s16x8 b, f32x4 c) {
  return __builtin_amdgcn_mfma_f32_16x16x32_bf16(a, b, c, 0, 0, 0);
}

typedef const __attribute__((address_space(1))) void* as1cptr;
typedef __attribute__((address_space(3))) void* as3ptr;
__device__ inline void gl2lds16(const short* g, short* l) {
  __builtin_amdgcn_global_load_lds((as1cptr)g, (as3ptr)l, 16, 0, 0);
}

// ---------------- fp32 -> bf16 conversion kernels --------------------------
__global__ void __launch_bounds__(256)
cvt2_kernel(const float* __restrict__ i0, const float* __restrict__ i1) {
  const int b = blockIdx.x;
  const float* src; short* dst; int base;
  if (b < 512) { src = i0; dst = g_srcb; base = b; }
  else         { src = i1; dst = g_inpwb; base = b - 512; }
  const int idx = (base * 256 + threadIdx.x) * 8;
  float4 a = *(const float4*)(src + idx);
  float4 c = *(const float4*)(src + idx + 4);
  *(s16x8*)(dst + idx) = pack8(a, c);
}

// all 6 layers' weights: inproj(2304) | outw(768) | ffw1(3072) | ffw2(3072)
__global__ void __launch_bounds__(256)
cvt6_kernel(const float* __restrict__ i0, const float* __restrict__ i1,
            const float* __restrict__ i2, const float* __restrict__ i3) {
  const int b = blockIdx.x;
  const float* src; short* dst; int base;
  if (b < 2304)      { src = i0; dst = g_wbuf;            base = b; }
  else if (b < 3072) { src = i1; dst = g_wbuf +  4718592; base = b - 2304; }
  else if (b < 6144) { src = i2; dst = g_wbuf +  6291456; base = b - 3072; }
  else               { src = i3; dst = g_wbuf + 12582912; base = b - 6144; }
  const int idx = (base * 256 + threadIdx.x) * 8;
  float4 a = *(const float4*)(src + idx);
  float4 c = *(const float4*)(src + idx + 4);
  *(s16x8*)(dst + idx) = pack8(a, c);
}

// ---------------- PE table: g_pe[s][n] ------------------------------------
__global__ void __launch_bounds__(256)
pe_kernel() {
  const int s = blockIdx.x;
  const int n0 = threadIdx.x * 2;
  const float ang = (float)s * expf((float)n0 * -0.0179889460390160f);
  g_pe[s * 512 + n0]     = sinf(ang);
  g_pe[s * 512 + n0 + 1] = cosf(ang);
}

// ---------------- GEMM: C[M,N] = A[M,K] @ W[N,K]^T + epilogue -------------
// BK=64, XOR-swizzled gl2lds staging, 1D bn-major grid (unchanged from R12).
template <int EPI>
__global__ void __launch_bounds__(256, 3)
gemm_bt(const short* __restrict__ Ain, int woff, const float* __restrict__ bias,
        short* __restrict__ C, int M, int N, int K) {
  __shared__ short As[128 * 64];   // 16 KB
  __shared__ short Bs[128 * 64];   // 16 KB
  const int tid  = threadIdx.x;
  const int lane = tid & 63;
  const int wave = tid >> 6;
  const int wr = (wave >> 1) << 6;
  const int wc = (wave & 1) << 6;
  const int ml = lane & 15;
  const int quad = lane >> 4;
  const int bm = blockIdx.x & 127;
  const int bn = blockIdx.x >> 7;

  const short* A = (EPI == 2) ? (const short*)g_srcb : Ain;
  const short* W = (EPI == 2) ? (const short*)g_inpwb : (const short*)(g_wbuf + woff);

  int srow[4], soff[4];
#pragma unroll
  for (int i = 0; i < 4; ++i) {
    const int u = i * 256 + tid;
    srow[i] = u >> 3;
    soff[i] = ((u & 7) ^ ((u >> 3) & 7)) << 3;
  }
  const int rsw = (ml & 7);
  f32x4 acc[4][4] = {};

  for (int k0 = 0; k0 < K; k0 += 64) {
#pragma unroll
    for (int i = 0; i < 4; ++i) {
      gl2lds16(A + (size_t)(bm * 128 + srow[i]) * K + k0 + soff[i],
               As + (i * 256 + tid) * 8);
      gl2lds16(W + (size_t)(bn * 128 + srow[i]) * K + k0 + soff[i],
               Bs + (i * 256 + tid) * 8);
    }
    __syncthreads();
#pragma unroll
    for (int kk = 0; kk < 2; ++kk) {
      const int rchunk = ((kk * 4 + quad) ^ rsw) * 8;
      s16x8 af[4], bfr[4];
#pragma unroll
      for (int i = 0; i < 4; ++i)
        af[i] = *(const s16x8*)(As + (wr + i * 16 + ml) * 64 + rchunk);
#pragma unroll
      for (int j = 0; j < 4; ++j)
        bfr[j] = *(const s16x8*)(Bs + (wc + j * 16 + ml) * 64 + rchunk);
#pragma unroll
      for (int i = 0; i < 4; ++i)
#pragma unroll
        for (int j = 0; j < 4; ++j)
          acc[i][j] = mfma16(af[i], bfr[j], acc[i][j]);
    }
    __syncthreads();
  }

#pragma unroll
  for (int j = 0; j < 4; ++j) {
    const int col = bn * 128 + wc + j * 16 + ml;
    const float bv = bias[col];
#pragma unroll
    for (int i = 0; i < 4; ++i) {
      const int row0 = bm * 128 + wr + i * 16 + quad * 4;
#pragma unroll
      for (int r = 0; r < 4; ++r) {
        float v = acc[i][j][r] + bv;
        if (EPI == 1) v = fmaxf(v, 0.0f);
        if (EPI == 2) {
          const int s = (row0 + r) & 511;
          v = (acc[i][j][r] + bv) * 22.62741699796952f + g_pe[s * 512 + col];
        }
        C[(size_t)(row0 + r) * N + col] = f2b(v);
      }
    }
  }
}

// ---------------- attention: R12 two-phase kernel widened to 512 threads --
// 8 waves = 4 m-tiles x 2 key/d-halves; 64 q-rows per block. Same staged
// K/V tile + same barrier count now serve 2x the rows (per-row cost halved).
// Grid 2048 with XCD-affine swizzle: bx = (bh&7) | (qt<<3) | ((bh>>3)<<6).
__global__ void __launch_bounds__(512, 4)
attn_kernel(const short* __restrict__ qkv, short* __restrict__ ctx) {
  __shared__ short KT[64 * 72];      // [key][d]
  __shared__ short VT[64 * 72];      // [d][key]
  __shared__ short Pt[64 * 72];      // [row][key]
  __shared__ float rcomb[2][4][16];  // [nh][mt][row16]: max, then sums
  const int tid = threadIdx.x;
  const int lane = tid & 63, wave = tid >> 6;
  const int ml = lane & 15, quad = lane >> 4;
  const int mt = wave >> 1, nh = wave & 1;
  const int qt = (blockIdx.x >> 3) & 7;
  const int bh = (blockIdx.x & 7) | ((blockIdx.x >> 6) << 3);
  const int b = bh >> 3, h = bh & 7;
  const size_t basebs = (size_t)b * 512 * 1536;
  const int hoff = h * 64;

  s16x8 qf0, qf1;
  {
    const int qrow = qt * 64 + mt * 16 + ml;
    const short* qp = qkv + basebs + (size_t)qrow * 1536 + hoff;
    qf0 = *(const s16x8*)(qp + quad * 8);
    qf1 = *(const s16x8*)(qp + 32 + quad * 8);
  }

  // ---- phase 1: all scores into registers (8 rounds x 64 keys) ----
  f32x4 sc[8][2];
#pragma unroll
  for (int rr = 0; rr < 8; ++rr) {
    {                                      // stage 64 keys x 64 d: 1 ld/thread
      const int key = tid >> 3;
      const int d8 = (tid & 7) << 3;
      const short* kp = qkv + basebs + (size_t)(rr * 64 + key) * 1536 + 512 + hoff + d8;
      *(s16x8*)(KT + key * 72 + d8) = *(const s16x8*)kp;
    }
    __syncthreads();
#pragma unroll
    for (int nt = 0; nt < 2; ++nt) {
      const int nrow = nh * 32 + nt * 16 + ml;
      f32x4 sacc = {};
      s16x8 kf0 = *(const s16x8*)(KT + nrow * 72 + quad * 8);
      s16x8 kf1 = *(const s16x8*)(KT + nrow * 72 + 32 + quad * 8);
      sacc = mfma16(qf0, kf0, sacc);
      sacc = mfma16(qf1, kf1, sacc);
      sc[rr][nt] = sacc;
    }
    __syncthreads();
  }

  // ---- exact row max ----
  f32x4 rmx = sc[0][0];
#pragma unroll
  for (int rr = 0; rr < 8; ++rr)
#pragma unroll
    for (int nt = 0; nt < 2; ++nt)
#pragma unroll
      for (int r = 0; r < 4; ++r)
        rmx[r] = fmaxf(rmx[r], sc[rr][nt][r]);
#pragma unroll
  for (int off = 1; off <= 8; off <<= 1)
#pragma unroll
    for (int r = 0; r < 4; ++r)
      rmx[r] = fmaxf(rmx[r], __shfl_xor(rmx[r], off));
  if (ml == 0) {
#pragma unroll
    for (int r = 0; r < 4; ++r)
      rcomb[nh][mt][quad * 4 + r] = rmx[r];
  }
  __syncthreads();
  float rm[4];
#pragma unroll
  for (int r = 0; r < 4; ++r)
    rm[r] = 0.125f * fmaxf(rcomb[0][mt][quad * 4 + r], rcomb[1][mt][quad * 4 + r]);

  // ---- phase 2: exp -> Pt, V^T stage, PV MFMA (8 rounds) ----
  f32x4 oacc[2] = {};
  float psum[4] = {0.f, 0.f, 0.f, 0.f};
#pragma unroll
  for (int rr = 0; rr < 8; ++rr) {
#pragma unroll
    for (int nt = 0; nt < 2; ++nt) {
#pragma unroll
      for (int r = 0; r < 4; ++r) {
        float p = __expf(sc[rr][nt][r] * 0.125f - rm[r]);   // arg <= 0 exactly
        short pb = f2b(p);
        psum[r] += b2f(pb);
        Pt[(mt * 16 + quad * 4 + r) * 72 + nh * 32 + nt * 16 + ml] = pb;
      }
    }
#pragma unroll
    for (int i = 0; i < 2; ++i) {          // stage V^T tile [d][key]
      const int u = i * 512 + tid;
      const int kp = u >> 5;   // key pair 0..31
      const int dp = u & 31;   // d pair 0..31
      const short* vp = qkv + basebs + (size_t)(rr * 64 + kp * 2) * 1536 + 1024 + hoff + dp * 2;
      unsigned int u0 = *(const unsigned int*)vp;
      unsigned int u1 = *(const unsigned int*)(vp + 1536);
      *(unsigned int*)(VT + (dp * 2) * 72 + kp * 2) = (u0 & 0xffffu) | (u1 << 16);
      *(unsigned int*)(VT + (dp * 2 + 1) * 72 + kp * 2) = (u0 >> 16) | (u1 & 0xffff0000u);
    }
    __syncthreads();   // Pt + VT visible
#pragma unroll
    for (int ks = 0; ks < 2; ++ks) {
      s16x8 pf = *(const s16x8*)(Pt + (mt * 16 + ml) * 72 + ks * 32 + quad * 8);
#pragma unroll
      for (int n2 = 0; n2 < 2; ++n2) {
        const int nd = (nh * 2 + n2) * 16 + ml;
        s16x8 vf = *(const s16x8*)(VT + nd * 72 + ks * 32 + quad * 8);
        oacc[n2] = mfma16(pf, vf, oacc[n2]);
      }
    }
    __syncthreads();   // PV reads done before next-round Pt/VT rewrite
  }

  // ---- row sums ----
#pragma unroll
  for (int off = 1; off <= 8; off <<= 1)
#pragma unroll
    for (int r = 0; r < 4; ++r)
      psum[r] += __shfl_xor(psum[r], off);
  if (ml == 0) {
#pragma unroll
    for (int r = 0; r < 4; ++r)
      rcomb[nh][mt][quad * 4 + r] = psum[r];
  }
  __syncthreads();

#pragma unroll
  for (int r = 0; r < 4; ++r) {
    const float l = rcomb[0][mt][quad * 4 + r] + rcomb[1][mt][quad * 4 + r];
    const float rl = 1.0f / l;
    const int grow = qt * 64 + mt * 16 + quad * 4 + r;
#pragma unroll
    for (int n2 = 0; n2 < 2; ++n2) {
      const int d = (nh * 2 + n2) * 16 + ml;
      ctx[((size_t)b * 512 + grow) * 512 + hoff + d] = f2b(oacc[n2][r] * rl);
    }
  }
}

// ---------------- residual + layernorm (in-place on x, fp32 params) -------
__global__ void __launch_bounds__(256)
ln_kernel(short* __restrict__ x, const short* __restrict__ o,
          const float* __restrict__ g, const float* __restrict__ bta) {
  const int row = blockIdx.x * 4 + (threadIdx.x >> 6);
  const int lane = threadIdx.x & 63;
  short* xp = x + (size_t)row * 512 + lane * 8;
  const short* op = o + (size_t)row * 512 + lane * 8;
  s16x8 xv = *(const s16x8*)xp;
  s16x8 ov = *(const s16x8*)op;
  float v[8]; float s = 0.f, s2 = 0.f;
#pragma unroll
  for (int e = 0; e < 8; ++e) {
    float f = b2f(xv[e]) + b2f(ov[e]);
    v[e] = f; s += f; s2 += f * f;
  }
#pragma unroll
  for (int off = 32; off >= 1; off >>= 1) {
    s += __shfl_xor(s, off);
    s2 += __shfl_xor(s2, off);
  }
  const float mean = s * (1.f / 512.f);
  const float var = s2 * (1.f / 512.f) - mean * mean;
  const float rstd = rsqrtf(var + 1e-5f);
  float4 g0 = *(const float4*)(g + lane * 8);
  float4 g1 = *(const float4*)(g + lane * 8 + 4);
  float4 b0 = *(const float4*)(bta + lane * 8);
  float4 b1 = *(const float4*)(bta + lane * 8 + 4);
  float gv[8] = {g0.x, g0.y, g0.z, g0.w, g1.x, g1.y, g1.z, g1.w};
  float bv[8] = {b0.x, b0.y, b0.z, b0.w, b1.x, b1.y, b1.z, b1.w};
  s16x8 outv;
#pragma unroll
  for (int e = 0; e < 8; ++e)
    outv[e] = f2b((v[e] - mean) * rstd * gv[e] + bv[e]);
  *(s16x8*)xp = outv;
}

// ---------------- head ----------------------------------------------------
__global__ void __launch_bounds__(256)
head1_kernel(const short* __restrict__ x, const float* __restrict__ w1,
             const float* __restrict__ b1, const float* __restrict__ w2) {
  const int bidx = blockIdx.x;
  const int b = bidx >> 3, seg = bidx & 7;
  const int tid = threadIdx.x;
  __shared__ float xl[512];
  __shared__ float red[256];
  for (int n = tid; n < 512; n += 256)
    xl[n] = b2f(x[((size_t)b * 512 + 511) * 512 + n]);
  __syncthreads();
  const int f = seg * 256 + tid;
  const float* wr = w1 + (size_t)f * 512;
  float hv = 0.f;
  for (int k8 = 0; k8 < 64; ++k8) {
    float4 wa = *(const float4*)(wr + k8 * 8);
    float4 wb = *(const float4*)(wr + k8 * 8 + 4);
    hv += xl[k8 * 8 + 0] * wa.x + xl[k8 * 8 + 1] * wa.y +
          xl[k8 * 8 + 2] * wa.z + xl[k8 * 8 + 3] * wa.w +
          xl[k8 * 8 + 4] * wb.x + xl[k8 * 8 + 5] * wb.y +
          xl[k8 * 8 + 6] * wb.z + xl[k8 * 8 + 7] * wb.w;
  }
  hv += b1[f];
  hv = fmaxf(hv, 0.f);
  red[tid] = hv * w2[f];
  __syncthreads();
  for (int stride = 128; stride > 0; stride >>= 1) {
    if (tid < stride) red[tid] += red[tid + stride];
    __syncthreads();
  }
  if (tid == 0) g_hpart[bidx] = red[0];
}

__global__ void __launch_bounds__(64)
head2_kernel(const float* __restrict__ b2, float* __restrict__ out) {
  const int t = threadIdx.x;
  if (t < 32) {
    float s = 0.f;
#pragma unroll
    for (int c = 0; c < 8; ++c) s += g_hpart[t * 8 + c];
    out[t] = s + b2[0];
  }
}

extern "C" void kernel_launch(void* const* d_in, const int* in_sizes, int n_in,
                              void* d_out, int out_size, void* d_ws, size_t ws_size,
                              hipStream_t stream) {
  (void)in_sizes; (void)n_in; (void)out_size; (void)ws_size;
  const float* src       = (const float*)d_in[0];
  const float* inp_w     = (const float*)d_in[1];
  const float* inp_b     = (const float*)d_in[2];
  const float* in_proj_w = (const float*)d_in[3];
  const float* in_proj_b = (const float*)d_in[4];
  const float* out_w     = (const float*)d_in[5];
  const float* out_b     = (const float*)d_in[6];
  const float* ff_w1     = (const float*)d_in[7];
  const float* ff_b1     = (const float*)d_in[8];
  const float* ff_w2     = (const float*)d_in[9];
  const float* ff_b2     = (const float*)d_in[10];
  const float* ln1_g     = (const float*)d_in[11];
  const float* ln1_b     = (const float*)d_in[12];
  const float* ln2_g     = (const float*)d_in[13];
  const float* ln2_b     = (const float*)d_in[14];
  const float* op_w1     = (const float*)d_in[15];
  const float* op_b1     = (const float*)d_in[16];
  const float* op_w2     = (const float*)d_in[17];
  const float* op_b2     = (const float*)d_in[18];

  short* ws   = (short*)d_ws;
  short* x    = ws;                              //  8,388,608
  short* qkv  = ws + 8388608;                    // 25,165,824
  short* ctx  = qkv + 25165824;                  //  8,388,608
  short* obuf = ctx + 8388608;                   //  8,388,608
  short* h    = qkv;                             // ff hidden spans qkv+ctx

  cvt2_kernel<<<528, 256, 0, stream>>>(src, inp_w);
  cvt6_kernel<<<9216, 256, 0, stream>>>(in_proj_w, out_w, ff_w1, ff_w2);
  pe_kernel<<<512, 256, 0, stream>>>();
  gemm_bt<2><<<512, 256, 0, stream>>>(nullptr, 0, inp_b, x, 16384, 512, 64);

  for (int l = 0; l < 6; ++l) {
    const int w_qkv = l * 786432;
    const int w_out = 4718592 + l * 262144;
    const int w_ff1 = 6291456 + l * 1048576;
    const int w_ff2 = 12582912 + l * 1048576;
    gemm_bt<0><<<1536, 256, 0, stream>>>(
        x, w_qkv, in_proj_b + l * 1536, qkv, 16384, 1536, 512);
    attn_kernel<<<2048, 512, 0, stream>>>(qkv, ctx);
    gemm_bt<0><<<512, 256, 0, stream>>>(
        ctx, w_out, out_b + l * 512, obuf, 16384, 512, 512);
    ln_kernel<<<4096, 256, 0, stream>>>(x, obuf, ln1_g + l * 512, ln1_b + l * 512);
    gemm_bt<1><<<2048, 256, 0, stream>>>(
        x, w_ff1, ff_b1 + l * 2048, h, 16384, 2048, 512);
    gemm_bt<0><<<512, 256, 0, stream>>>(
        h, w_ff2, ff_b2 + l * 512, obuf, 16384, 512, 2048);
    ln_kernel<<<4096, 256, 0, stream>>>(x, obuf, ln2_g + l * 512, ln2_b + l * 512);
  }
  head1_kernel<<<256, 256, 0, stream>>>(x, op_w1, op_b1, op_w2);
  head2_kernel<<<1, 64, 0, stream>>>(op_b2, (float*)d_out);
}

// Round 14
// 1525.970 us; speedup vs baseline: 1.3211x; 1.0159x over previous
//
#include <hip/hip_runtime.h>

typedef short s16x8 __attribute__((ext_vector_type(8)));
typedef float f32x4 __attribute__((ext_vector_type(4)));
typedef float f32x16 __attribute__((ext_vector_type(16)));

// device-global scratch (outside d_ws; fully rewritten every launch)
__device__ short g_wbuf[18874368];  // bf16 weights, all layers: inproj|outw|ffw1|ffw2
__device__ short g_srcb[1048576];   // src as bf16 (16384 x 64)
__device__ short g_inpwb[32768];    // inp_w as bf16 (512 x 64)
__device__ float g_pe[262144];      // positional encoding (512 x 512)
__device__ float g_hpart[256];      // head partials

__device__ inline float b2f(short s) {
  union { unsigned int u; float f; } v;
  v.u = ((unsigned int)(unsigned short)s) << 16;
  return v.f;
}
__device__ inline short f2b(float f) {
  union { float f; unsigned int u; } v; v.f = f;
  unsigned int r = (v.u + 0x7fffu + ((v.u >> 16) & 1u)) >> 16;
  return (short)r;
}
__device__ inline s16x8 pack8(float4 a, float4 b) {
  s16x8 r;
  r[0] = f2b(a.x); r[1] = f2b(a.y); r[2] = f2b(a.z); r[3] = f2b(a.w);
  r[4] = f2b(b.x); r[5] = f2b(b.y); r[6] = f2b(b.z); r[7] = f2b(b.w);
  return r;
}

__device__ inline f32x4 mfma16(s16x8 a, s16x8 b, f32x4 c) {
  return __builtin_amdgcn_mfma_f32_16x16x32_bf16(a, b, c, 0, 0, 0);
}
__device__ inline f32x16 mfma32(s16x8 a, s16x8 b, f32x16 c) {
  return __builtin_amdgcn_mfma_f32_32x32x16_bf16(a, b, c, 0, 0, 0);
}

typedef const __attribute__((address_space(1))) void* as1cptr;
typedef __attribute__((address_space(3))) void* as3ptr;
__device__ inline void gl2lds16(const short* g, short* l) {
  __builtin_amdgcn_global_load_lds((as1cptr)g, (as3ptr)l, 16, 0, 0);
}

// ---------------- fp32 -> bf16 conversion kernels --------------------------
__global__ void __launch_bounds__(256)
cvt2_kernel(const float* __restrict__ i0, const float* __restrict__ i1) {
  const int b = blockIdx.x;
  const float* src; short* dst; int base;
  if (b < 512) { src = i0; dst = g_srcb; base = b; }
  else         { src = i1; dst = g_inpwb; base = b - 512; }
  const int idx = (base * 256 + threadIdx.x) * 8;
  float4 a = *(const float4*)(src + idx);
  float4 c = *(const float4*)(src + idx + 4);
  *(s16x8*)(dst + idx) = pack8(a, c);
}

// all 6 layers' weights: inproj(2304) | outw(768) | ffw1(3072) | ffw2(3072)
__global__ void __launch_bounds__(256)
cvt6_kernel(const float* __restrict__ i0, const float* __restrict__ i1,
            const float* __restrict__ i2, const float* __restrict__ i3) {
  const int b = blockIdx.x;
  const float* src; short* dst; int base;
  if (b < 2304)      { src = i0; dst = g_wbuf;            base = b; }
  else if (b < 3072) { src = i1; dst = g_wbuf +  4718592; base = b - 2304; }
  else if (b < 6144) { src = i2; dst = g_wbuf +  6291456; base = b - 3072; }
  else               { src = i3; dst = g_wbuf + 12582912; base = b - 6144; }
  const int idx = (base * 256 + threadIdx.x) * 8;
  float4 a = *(const float4*)(src + idx);
  float4 c = *(const float4*)(src + idx + 4);
  *(s16x8*)(dst + idx) = pack8(a, c);
}

// ---------------- PE table: g_pe[s][n] ------------------------------------
__global__ void __launch_bounds__(256)
pe_kernel() {
  const int s = blockIdx.x;
  const int n0 = threadIdx.x * 2;
  const float ang = (float)s * expf((float)n0 * -0.0179889460390160f);
  g_pe[s * 512 + n0]     = sinf(ang);
  g_pe[s * 512 + n0 + 1] = cosf(ang);
}

// ---------------- GEMM: C[M,N] = A[M,K] @ W[N,K]^T + epilogue -------------
// BK=64, XOR-swizzled gl2lds staging, 1D bn-major grid. Core switched to
// 32x32x16 MFMA: per wave 2x2 tiles of 32x32, 16 MFMA/BK64 (was 32), same
// LDS bytes. C/D map (HW-verified m74/m101): col=lane&31,
// row=(reg&3)+8*(reg>>2)+4*(lane>>5). A/B k-map assumption cancels by
// A/B symmetry. EPI: 0=+bias; 1=relu; 2=embed.
template <int EPI>
__global__ void __launch_bounds__(256, 3)
gemm_bt(const short* __restrict__ Ain, int woff, const float* __restrict__ bias,
        short* __restrict__ C, int M, int N, int K) {
  __shared__ short As[128 * 64];   // 16 KB
  __shared__ short Bs[128 * 64];   // 16 KB
  const int tid  = threadIdx.x;
  const int lane = tid & 63;
  const int wave = tid >> 6;
  const int wr = (wave >> 1) << 6;
  const int wc = (wave & 1) << 6;
  const int l31 = lane & 31;
  const int half = lane >> 5;          // 0/1: k-half within K=16 step
  const int bm = blockIdx.x & 127;
  const int bn = blockIdx.x >> 7;

  const short* A = (EPI == 2) ? (const short*)g_srcb : Ain;
  const short* W = (EPI == 2) ? (const short*)g_inpwb : (const short*)(g_wbuf + woff);

  int srow[4], soff[4];
#pragma unroll
  for (int i = 0; i < 4; ++i) {
    const int u = i * 256 + tid;
    srow[i] = u >> 3;
    soff[i] = ((u & 7) ^ ((u >> 3) & 7)) << 3;
  }
  const int rsw = lane & 7;            // read-side swizzle key (row&7)
  f32x16 acc[2][2] = {};

  for (int k0 = 0; k0 < K; k0 += 64) {
#pragma unroll
    for (int i = 0; i < 4; ++i) {
      gl2lds16(A + (size_t)(bm * 128 + srow[i]) * K + k0 + soff[i],
               As + (i * 256 + tid) * 8);
      gl2lds16(W + (size_t)(bn * 128 + srow[i]) * K + k0 + soff[i],
               Bs + (i * 256 + tid) * 8);
    }
    __syncthreads();
#pragma unroll
    for (int ks = 0; ks < 4; ++ks) {
      const int rchunk = ((ks * 2 + half) ^ rsw) * 8;
      s16x8 af[2], bfr[2];
#pragma unroll
      for (int i = 0; i < 2; ++i)
        af[i] = *(const s16x8*)(As + (wr + i * 32 + l31) * 64 + rchunk);
#pragma unroll
      for (int j = 0; j < 2; ++j)
        bfr[j] = *(const s16x8*)(Bs + (wc + j * 32 + l31) * 64 + rchunk);
#pragma unroll
      for (int i = 0; i < 2; ++i)
#pragma unroll
        for (int j = 0; j < 2; ++j)
          acc[i][j] = mfma32(af[i], bfr[j], acc[i][j]);
    }
    __syncthreads();
  }

#pragma unroll
  for (int j = 0; j < 2; ++j) {
    const int col = bn * 128 + wc + j * 32 + l31;
    const float bv = bias[col];
#pragma unroll
    for (int i = 0; i < 2; ++i) {
      const int rbase = bm * 128 + wr + i * 32 + half * 4;
#pragma unroll
      for (int r = 0; r < 16; ++r) {
        const int row = rbase + (r & 3) + 8 * (r >> 2);
        float v = acc[i][j][r] + bv;
        if (EPI == 1) v = fmaxf(v, 0.0f);
        if (EPI == 2) {
          const int s = row & 511;
          v = (acc[i][j][r] + bv) * 22.62741699796952f + g_pe[s * 512 + col];
        }
        C[(size_t)row * N + col] = f2b(v);
      }
    }
  }
}

// ---------------- attention: R13 512-thread two-phase kernel (plateaued) --
__global__ void __launch_bounds__(512, 4)
attn_kernel(const short* __restrict__ qkv, short* __restrict__ ctx) {
  __shared__ short KT[64 * 72];      // [key][d]
  __shared__ short VT[64 * 72];      // [d][key]
  __shared__ short Pt[64 * 72];      // [row][key]
  __shared__ float rcomb[2][4][16];  // [nh][mt][row16]: max, then sums
  const int tid = threadIdx.x;
  const int lane = tid & 63, wave = tid >> 6;
  const int ml = lane & 15, quad = lane >> 4;
  const int mt = wave >> 1, nh = wave & 1;
  const int qt = (blockIdx.x >> 3) & 7;
  const int bh = (blockIdx.x & 7) | ((blockIdx.x >> 6) << 3);
  const int b = bh >> 3, h = bh & 7;
  const size_t basebs = (size_t)b * 512 * 1536;
  const int hoff = h * 64;

  s16x8 qf0, qf1;
  {
    const int qrow = qt * 64 + mt * 16 + ml;
    const short* qp = qkv + basebs + (size_t)qrow * 1536 + hoff;
    qf0 = *(const s16x8*)(qp + quad * 8);
    qf1 = *(const s16x8*)(qp + 32 + quad * 8);
  }

  // ---- phase 1: all scores into registers (8 rounds x 64 keys) ----
  f32x4 sc[8][2];
#pragma unroll
  for (int rr = 0; rr < 8; ++rr) {
    {                                      // stage 64 keys x 64 d: 1 ld/thread
      const int key = tid >> 3;
      const int d8 = (tid & 7) << 3;
      const short* kp = qkv + basebs + (size_t)(rr * 64 + key) * 1536 + 512 + hoff + d8;
      *(s16x8*)(KT + key * 72 + d8) = *(const s16x8*)kp;
    }
    __syncthreads();
#pragma unroll
    for (int nt = 0; nt < 2; ++nt) {
      const int nrow = nh * 32 + nt * 16 + ml;
      f32x4 sacc = {};
      s16x8 kf0 = *(const s16x8*)(KT + nrow * 72 + quad * 8);
      s16x8 kf1 = *(const s16x8*)(KT + nrow * 72 + 32 + quad * 8);
      sacc = mfma16(qf0, kf0, sacc);
      sacc = mfma16(qf1, kf1, sacc);
      sc[rr][nt] = sacc;
    }
    __syncthreads();
  }

  // ---- exact row max ----
  f32x4 rmx = sc[0][0];
#pragma unroll
  for (int rr = 0; rr < 8; ++rr)
#pragma unroll
    for (int nt = 0; nt < 2; ++nt)
#pragma unroll
      for (int r = 0; r < 4; ++r)
        rmx[r] = fmaxf(rmx[r], sc[rr][nt][r]);
#pragma unroll
  for (int off = 1; off <= 8; off <<= 1)
#pragma unroll
    for (int r = 0; r < 4; ++r)
      rmx[r] = fmaxf(rmx[r], __shfl_xor(rmx[r], off));
  if (ml == 0) {
#pragma unroll
    for (int r = 0; r < 4; ++r)
      rcomb[nh][mt][quad * 4 + r] = rmx[r];
  }
  __syncthreads();
  float rm[4];
#pragma unroll
  for (int r = 0; r < 4; ++r)
    rm[r] = 0.125f * fmaxf(rcomb[0][mt][quad * 4 + r], rcomb[1][mt][quad * 4 + r]);

  // ---- phase 2: exp -> Pt, V^T stage, PV MFMA (8 rounds) ----
  f32x4 oacc[2] = {};
  float psum[4] = {0.f, 0.f, 0.f, 0.f};
#pragma unroll
  for (int rr = 0; rr < 8; ++rr) {
#pragma unroll
    for (int nt = 0; nt < 2; ++nt) {
#pragma unroll
      for (int r = 0; r < 4; ++r) {
        float p = __expf(sc[rr][nt][r] * 0.125f - rm[r]);   // arg <= 0 exactly
        short pb = f2b(p);
        psum[r] += b2f(pb);
        Pt[(mt * 16 + quad * 4 + r) * 72 + nh * 32 + nt * 16 + ml] = pb;
      }
    }
#pragma unroll
    for (int i = 0; i < 2; ++i) {          // stage V^T tile [d][key]
      const int u = i * 512 + tid;
      const int kp = u >> 5;   // key pair 0..31
      const int dp = u & 31;   // d pair 0..31
      const short* vp = qkv + basebs + (size_t)(rr * 64 + kp * 2) * 1536 + 1024 + hoff + dp * 2;
      unsigned int u0 = *(const unsigned int*)vp;
      unsigned int u1 = *(const unsigned int*)(vp + 1536);
      *(unsigned int*)(VT + (dp * 2) * 72 + kp * 2) = (u0 & 0xffffu) | (u1 << 16);
      *(unsigned int*)(VT + (dp * 2 + 1) * 72 + kp * 2) = (u0 >> 16) | (u1 & 0xffff0000u);
    }
    __syncthreads();   // Pt + VT visible
#pragma unroll
    for (int ks = 0; ks < 2; ++ks) {
      s16x8 pf = *(const s16x8*)(Pt + (mt * 16 + ml) * 72 + ks * 32 + quad * 8);
#pragma unroll
      for (int n2 = 0; n2 < 2; ++n2) {
        const int nd = (nh * 2 + n2) * 16 + ml;
        s16x8 vf = *(const s16x8*)(VT + nd * 72 + ks * 32 + quad * 8);
        oacc[n2] = mfma16(pf, vf, oacc[n2]);
      }
    }
    __syncthreads();   // PV reads done before next-round Pt/VT rewrite
  }

  // ---- row sums ----
#pragma unroll
  for (int off = 1; off <= 8; off <<= 1)
#pragma unroll
    for (int r = 0; r < 4; ++r)
      psum[r] += __shfl_xor(psum[r], off);
  if (ml == 0) {
#pragma unroll
    for (int r = 0; r < 4; ++r)
      rcomb[nh][mt][quad * 4 + r] = psum[r];
  }
  __syncthreads();

#pragma unroll
  for (int r = 0; r < 4; ++r) {
    const float l = rcomb[0][mt][quad * 4 + r] + rcomb[1][mt][quad * 4 + r];
    const float rl = 1.0f / l;
    const int grow = qt * 64 + mt * 16 + quad * 4 + r;
#pragma unroll
    for (int n2 = 0; n2 < 2; ++n2) {
      const int d = (nh * 2 + n2) * 16 + ml;
      ctx[((size_t)b * 512 + grow) * 512 + hoff + d] = f2b(oacc[n2][r] * rl);
    }
  }
}

// ---------------- residual + layernorm (in-place on x, fp32 params) -------
__global__ void __launch_bounds__(256)
ln_kernel(short* __restrict__ x, const short* __restrict__ o,
          const float* __restrict__ g, const float* __restrict__ bta) {
  const int row = blockIdx.x * 4 + (threadIdx.x >> 6);
  const int lane = threadIdx.x & 63;
  short* xp = x + (size_t)row * 512 + lane * 8;
  const short* op = o + (size_t)row * 512 + lane * 8;
  s16x8 xv = *(const s16x8*)xp;
  s16x8 ov = *(const s16x8*)op;
  float v[8]; float s = 0.f, s2 = 0.f;
#pragma unroll
  for (int e = 0; e < 8; ++e) {
    float f = b2f(xv[e]) + b2f(ov[e]);
    v[e] = f; s += f; s2 += f * f;
  }
#pragma unroll
  for (int off = 32; off >= 1; off >>= 1) {
    s += __shfl_xor(s, off);
    s2 += __shfl_xor(s2, off);
  }
  const float mean = s * (1.f / 512.f);
  const float var = s2 * (1.f / 512.f) - mean * mean;
  const float rstd = rsqrtf(var + 1e-5f);
  float4 g0 = *(const float4*)(g + lane * 8);
  float4 g1 = *(const float4*)(g + lane * 8 + 4);
  float4 b0 = *(const float4*)(bta + lane * 8);
  float4 b1 = *(const float4*)(bta + lane * 8 + 4);
  float gv[8] = {g0.x, g0.y, g0.z, g0.w, g1.x, g1.y, g1.z, g1.w};
  float bv[8] = {b0.x, b0.y, b0.z, b0.w, b1.x, b1.y, b1.z, b1.w};
  s16x8 outv;
#pragma unroll
  for (int e = 0; e < 8; ++e)
    outv[e] = f2b((v[e] - mean) * rstd * gv[e] + bv[e]);
  *(s16x8*)xp = outv;
}

// ---------------- head ----------------------------------------------------
__global__ void __launch_bounds__(256)
head1_kernel(const short* __restrict__ x, const float* __restrict__ w1,
             const float* __restrict__ b1, const float* __restrict__ w2) {
  const int bidx = blockIdx.x;
  const int b = bidx >> 3, seg = bidx & 7;
  const int tid = threadIdx.x;
  __shared__ float xl[512];
  __shared__ float red[256];
  for (int n = tid; n < 512; n += 256)
    xl[n] = b2f(x[((size_t)b * 512 + 511) * 512 + n]);
  __syncthreads();
  const int f = seg * 256 + tid;
  const float* wr = w1 + (size_t)f * 512;
  float hv = 0.f;
  for (int k8 = 0; k8 < 64; ++k8) {
    float4 wa = *(const float4*)(wr + k8 * 8);
    float4 wb = *(const float4*)(wr + k8 * 8 + 4);
    hv += xl[k8 * 8 + 0] * wa.x + xl[k8 * 8 + 1] * wa.y +
          xl[k8 * 8 + 2] * wa.z + xl[k8 * 8 + 3] * wa.w +
          xl[k8 * 8 + 4] * wb.x + xl[k8 * 8 + 5] * wb.y +
          xl[k8 * 8 + 6] * wb.z + xl[k8 * 8 + 7] * wb.w;
  }
  hv += b1[f];
  hv = fmaxf(hv, 0.f);
  red[tid] = hv * w2[f];
  __syncthreads();
  for (int stride = 128; stride > 0; stride >>= 1) {
    if (tid < stride) red[tid] += red[tid + stride];
    __syncthreads();
  }
  if (tid == 0) g_hpart[bidx] = red[0];
}

__global__ void __launch_bounds__(64)
head2_kernel(const float* __restrict__ b2, float* __restrict__ out) {
  const int t = threadIdx.x;
  if (t < 32) {
    float s = 0.f;
#pragma unroll
    for (int c = 0; c < 8; ++c) s += g_hpart[t * 8 + c];
    out[t] = s + b2[0];
  }
}

extern "C" void kernel_launch(void* const* d_in, const int* in_sizes, int n_in,
                              void* d_out, int out_size, void* d_ws, size_t ws_size,
                              hipStream_t stream) {
  (void)in_sizes; (void)n_in; (void)out_size; (void)ws_size;
  const float* src       = (const float*)d_in[0];
  const float* inp_w     = (const float*)d_in[1];
  const float* inp_b     = (const float*)d_in[2];
  const float* in_proj_w = (const float*)d_in[3];
  const float* in_proj_b = (const float*)d_in[4];
  const float* out_w     = (const float*)d_in[5];
  const float* out_b     = (const float*)d_in[6];
  const float* ff_w1     = (const float*)d_in[7];
  const float* ff_b1     = (const float*)d_in[8];
  const float* ff_w2     = (const float*)d_in[9];
  const float* ff_b2     = (const float*)d_in[10];
  const float* ln1_g     = (const float*)d_in[11];
  const float* ln1_b     = (const float*)d_in[12];
  const float* ln2_g     = (const float*)d_in[13];
  const float* ln2_b     = (const float*)d_in[14];
  const float* op_w1     = (const float*)d_in[15];
  const float* op_b1     = (const float*)d_in[16];
  const float* op_w2     = (const float*)d_in[17];
  const float* op_b2     = (const float*)d_in[18];

  short* ws   = (short*)d_ws;
  short* x    = ws;                              //  8,388,608
  short* qkv  = ws + 8388608;                    // 25,165,824
  short* ctx  = qkv + 25165824;                  //  8,388,608
  short* obuf = ctx + 8388608;                   //  8,388,608
  short* h    = qkv;                             // ff hidden spans qkv+ctx

  cvt2_kernel<<<528, 256, 0, stream>>>(src, inp_w);
  cvt6_kernel<<<9216, 256, 0, stream>>>(in_proj_w, out_w, ff_w1, ff_w2);
  pe_kernel<<<512, 256, 0, stream>>>();
  gemm_bt<2><<<512, 256, 0, stream>>>(nullptr, 0, inp_b, x, 16384, 512, 64);

  for (int l = 0; l < 6; ++l) {
    const int w_qkv = l * 786432;
    const int w_out = 4718592 + l * 262144;
    const int w_ff1 = 6291456 + l * 1048576;
    const int w_ff2 = 12582912 + l * 1048576;
    gemm_bt<0><<<1536, 256, 0, stream>>>(
        x, w_qkv, in_proj_b + l * 1536, qkv, 16384, 1536, 512);
    attn_kernel<<<2048, 512, 0, stream>>>(qkv, ctx);
    gemm_bt<0><<<512, 256, 0, stream>>>(
        ctx, w_out, out_b + l * 512, obuf, 16384, 512, 512);
    ln_kernel<<<4096, 256, 0, stream>>>(x, obuf, ln1_g + l * 512, ln1_b + l * 512);
    gemm_bt<1><<<2048, 256, 0, stream>>>(
        x, w_ff1, ff_b1 + l * 2048, h, 16384, 2048, 512);
    gemm_bt<0><<<512, 256, 0, stream>>>(
        h, w_ff2, ff_b2 + l * 512, obuf, 16384, 512, 2048);
    ln_kernel<<<4096, 256, 0, stream>>>(x, obuf, ln2_g + l * 512, ln2_b + l * 512);
  }
  head1_kernel<<<256, 256, 0, stream>>>(x, op_w1, op_b1, op_w2);
  head2_kernel<<<1, 64, 0, stream>>>(op_b2, (float*)d_out);
}